// Round 5
// baseline (1011.434 us; speedup 1.0000x reference)
//
#include <hip/hip_runtime.h>

#define LOG2E 1.4426950408889634f
#define TWO_LOG2E 2.8853900817779268f

typedef float v2f __attribute__((ext_vector_type(2)));

#if __has_builtin(__builtin_amdgcn_exp2f)
__device__ __forceinline__ float fexp2(float x){ return __builtin_amdgcn_exp2f(x); }
#else
__device__ __forceinline__ float fexp2(float x){ return exp2f(x); }
#endif
#if __has_builtin(__builtin_amdgcn_rcpf)
__device__ __forceinline__ float frcp(float x){ return __builtin_amdgcn_rcpf(x); }
#else
__device__ __forceinline__ float frcp(float x){ return 1.0f/(x); }
#endif

// DPP cross-lane move (full-rate VALU, no LDS pipe)
template<int CTRL>
__device__ __forceinline__ float dpp_f(float x) {
    return __int_as_float(__builtin_amdgcn_update_dpp(0, __float_as_int(x), CTRL, 0xF, 0xF, true));
}
#define DPP_XOR1  0xB1   // quad_perm(1,0,3,2)
#define DPP_XOR2  0x4E   // quad_perm(2,3,0,1)
#define DPP_BC0   0x00   // quad bcast lane0
#define DPP_BC1   0x55
#define DPP_BC2   0xAA
#define DPP_BC3   0xFF

// ---- layer-0 pre GEMM with fused embedding gather + csum zeroing ----------
__global__ __launch_bounds__(256) void gemm_l0(
    const int* __restrict__ wid, const int* __restrict__ tgi,
    const float* __restrict__ wemb, const float* __restrict__ temb,
    const float* __restrict__ Wa, const float* __restrict__ Wb,
    const float* __restrict__ b1a, const float* __restrict__ b1b,
    const float* __restrict__ b2a, const float* __restrict__ b2b,
    float* __restrict__ Ca, float* __restrict__ Cb,
    float* __restrict__ csum)
{
    int tid = threadIdx.x;
    if (blockIdx.x == 0 && blockIdx.y == 0 && blockIdx.z == 0) {
        csum[tid] = 0.f; csum[tid + 256] = 0.f;   // zero for score's atomics
    }
    int z = blockIdx.z;
    const float* W   = z ? Wb  : Wa;
    const float* bb1 = z ? b1b : b1a;
    const float* bb2 = z ? b2b : b2a;
    float* C = z ? Cb : Ca;

    __shared__ float Xs[64*33];
    __shared__ float Ws[64*33];
    int tx = tid & 15, ty = tid >> 4;
    int n0 = blockIdx.y*64, r0 = blockIdx.x*64;
    float acc[4][4] = {};

    for (int k0 = 0; k0 < 128; k0 += 32) {
        #pragma unroll
        for (int i = 0; i < 2; ++i) {
            int idx = tid + 256*i;
            int row = idx >> 3, c4 = idx & 7;
            int k = k0 + c4*4;
            int rg = n0 + row;
            float4 vx = (k < 100) ? *(const float4*)(wemb + wid[rg]*100 + k)
                                  : *(const float4*)(temb + tgi[rg]*28 + (k-100));
            float4 vw = *(const float4*)(W + (r0+row)*128 + k0 + c4*4);
            Xs[row*33 + c4*4+0]=vx.x; Xs[row*33 + c4*4+1]=vx.y; Xs[row*33 + c4*4+2]=vx.z; Xs[row*33 + c4*4+3]=vx.w;
            Ws[row*33 + c4*4+0]=vw.x; Ws[row*33 + c4*4+1]=vw.y; Ws[row*33 + c4*4+2]=vw.z; Ws[row*33 + c4*4+3]=vw.w;
        }
        __syncthreads();
        #pragma unroll 8
        for (int kk = 0; kk < 32; ++kk) {
            float a[4], b[4];
            #pragma unroll
            for (int i = 0; i < 4; ++i) a[i] = Xs[(4*ty+i)*33 + kk];
            #pragma unroll
            for (int j = 0; j < 4; ++j) b[j] = Ws[(4*tx+j)*33 + kk];
            #pragma unroll
            for (int i = 0; i < 4; ++i)
                #pragma unroll
                for (int j = 0; j < 4; ++j)
                    acc[i][j] = fmaf(a[i], b[j], acc[i][j]);
        }
        __syncthreads();
    }
    #pragma unroll
    for (int i = 0; i < 4; ++i)
        #pragma unroll
        for (int j = 0; j < 4; ++j) {
            int r = r0 + 4*tx + j;
            C[(n0 + 4*ty + i)*512 + r] = acc[i][j] + bb1[r] + bb2[r];
        }
}

// ------------- generic fused-pair GEMM: C[n][r] = scale*(X·W^T + b1 + b2) ----
__global__ __launch_bounds__(256) void gemm2(
    const float* __restrict__ X, int ldx,
    const float* __restrict__ Wa, const float* __restrict__ Wb, int ldw, int woffb,
    const float* __restrict__ b1a, const float* __restrict__ b1b,
    const float* __restrict__ b2a, const float* __restrict__ b2b,
    float* __restrict__ Ca, float* __restrict__ Cb,
    int K, float scale)
{
    int z = blockIdx.z;
    const float* W  = z ? Wb  : Wa;
    const float* bb1 = z ? b1b : b1a;
    const float* bb2 = z ? b2b : b2a;
    float* C = z ? Cb : Ca;
    int woff = z ? woffb : 0;

    __shared__ float Xs[64*33];
    __shared__ float Ws[64*33];
    int tid = threadIdx.x;
    int tx = tid & 15, ty = tid >> 4;
    int n0 = blockIdx.y*64, r0 = blockIdx.x*64;
    float acc[4][4] = {};

    for (int k0 = 0; k0 < K; k0 += 32) {
        #pragma unroll
        for (int i = 0; i < 2; ++i) {
            int idx = tid + 256*i;
            int row = idx >> 3, c4 = idx & 7;
            float4 vx = *(const float4*)(X + (n0+row)*ldx + k0 + c4*4);
            float4 vw = *(const float4*)(W + (r0+row)*ldw + woff + k0 + c4*4);
            Xs[row*33 + c4*4+0]=vx.x; Xs[row*33 + c4*4+1]=vx.y; Xs[row*33 + c4*4+2]=vx.z; Xs[row*33 + c4*4+3]=vx.w;
            Ws[row*33 + c4*4+0]=vw.x; Ws[row*33 + c4*4+1]=vw.y; Ws[row*33 + c4*4+2]=vw.z; Ws[row*33 + c4*4+3]=vw.w;
        }
        __syncthreads();
        #pragma unroll 8
        for (int kk = 0; kk < 32; ++kk) {
            float a[4], b[4];
            #pragma unroll
            for (int i = 0; i < 4; ++i) a[i] = Xs[(4*ty+i)*33 + kk];
            #pragma unroll
            for (int j = 0; j < 4; ++j) b[j] = Ws[(4*tx+j)*33 + kk];
            #pragma unroll
            for (int i = 0; i < 4; ++i)
                #pragma unroll
                for (int j = 0; j < 4; ++j)
                    acc[i][j] = fmaf(a[i], b[j], acc[i][j]);
        }
        __syncthreads();
    }
    #pragma unroll
    for (int i = 0; i < 4; ++i)
        #pragma unroll
        for (int j = 0; j < 4; ++j) {
            int r = r0 + 4*tx + j;
            float v = acc[i][j];
            if (bb1) v += bb1[r];
            if (bb2) v += bb2[r];
            C[(n0 + 4*ty + i)*512 + r] = v*scale;
        }
}

// ---------------- LSTM: 256 threads, 256 weights/thread (C=32, R=8) ---------
// lane: sub = tid&3 (col slice of 32), group g = tid>>2 owns cells j0=2g, j1=2g+1,
// all 4 gate-rows of each. 128 pk_fma/lane; 2-step quad DPP reduce; gate sub's
// sigmoid per lane (both cells), quad-broadcast share; both cells updated
// redundantly in-quad. hout store deferred one step (drains during compute).
__global__ __launch_bounds__(256, 1) void lstm_kernel(
    const float* __restrict__ preF, const float* __restrict__ preB,
    const float* __restrict__ WhhF, const float* __restrict__ WhhB,
    const float* __restrict__ h0, const float* __restrict__ c0,
    float* __restrict__ hout, int layer)
{
    const int dir = blockIdx.x;
    const int tid = threadIdx.x;
    const int sub = tid & 3;        // col slice 0..3 (cols 32*sub..+32)
    const int g   = tid >> 2;       // 0..63
    const int j0  = 2*g, j1 = 2*g + 1;
    const int q   = sub;            // gate handled by this lane's transcendental
    const float* Whh  = dir ? WhhB : WhhF;
    const float* preD = dir ? preB : preF;

    // ---- weights: w2[r][.] with r = cell*4 + gate; bank-rotated chunk order --
    v2f w2[8][16];
    {
        #pragma unroll
        for (int cc = 0; cc < 2; ++cc)
            #pragma unroll
            for (int qq = 0; qq < 4; ++qq) {
                const float* wr = Whh + ((qq << 7) + j0 + cc)*128 + (sub << 5);
                #pragma unroll
                for (int k = 0; k < 8; ++k) {
                    int kk = (k + 2*sub) & 7;
                    float4 v = *(const float4*)(wr + 4*kk);
                    w2[cc*4+qq][2*k+0] = (v2f){v.x, v.y};
                    w2[cc*4+qq][2*k+1] = (v2f){v.z, v.w};
                }
            }
    }

    __shared__ __align__(16) float hbuf[2][128];

    const float* h0d = h0 + (2*layer + dir)*128;
    const float* c0d = c0 + (2*layer + dir)*128;
    float c0v = c0d[j0];
    float c1v = c0d[j1];
    if (tid < 128) hbuf[0][tid] = h0d[tid];

    const float sc = (q == 2) ? -TWO_LOG2E : -LOG2E;   // gate 2: sigm(2*gg)
    const int prow0 = (q << 7) + j0;
    const int prow1 = (q << 7) + j1;
    const int t0 = dir ? 511 : 0;
    const int dt = dir ? -1 : 1;
    const int houtbase = dir*128;

    // LDS float4 chunk indices: instr k hits 4 distinct bank-groups, 16-lane bcast
    int cidx[8];
    #pragma unroll
    for (int k = 0; k < 8; ++k) cidx[k] = (sub << 3) + ((k + 2*sub) & 7);

    float p0 = preD[t0*512 + prow0];
    float p1 = preD[t0*512 + prow1];
    float hpv0 = 0.f, hpv1 = 0.f;
    __syncthreads();

    #pragma unroll 2
    for (int s = 0; s < 512; ++s) {
        const int t  = t0 + dt*s;

        // deferred hout store of PREVIOUS step (s=0: garbage to t0, overwritten at s=1)
        const int tp = (s == 0) ? t : (t - dt);
        if (sub == 2) hout[tp*256 + houtbase + j0] = hpv0;
        if (sub == 3) hout[tp*256 + houtbase + j1] = hpv1;

        // prefetch next pre
        const int tn = (s < 511) ? (t + dt) : t;
        float pn0 = preD[tn*512 + prow0];
        float pn1 = preD[tn*512 + prow1];

        const float4* h4 = (const float4*)hbuf[s & 1];
        v2f acc2[8] = {(v2f)0.f,(v2f)0.f,(v2f)0.f,(v2f)0.f,
                       (v2f)0.f,(v2f)0.f,(v2f)0.f,(v2f)0.f};
        #pragma unroll
        for (int k = 0; k < 8; ++k) {
            float4 hv = h4[cidx[k]];
            v2f hp0 = (v2f){hv.x, hv.y};
            v2f hp1 = (v2f){hv.z, hv.w};
            #pragma unroll
            for (int r = 0; r < 8; ++r) {
                acc2[r] = __builtin_elementwise_fma(hp0, w2[r][2*k+0], acc2[r]);
                acc2[r] = __builtin_elementwise_fma(hp1, w2[r][2*k+1], acc2[r]);
            }
        }

        // quad butterfly reduce over the 4 col-slices
        float accf[8];
        #pragma unroll
        for (int r = 0; r < 8; ++r) {
            float a = acc2[r].x + acc2[r].y;
            a += dpp_f<DPP_XOR1>(a);
            a += dpp_f<DPP_XOR2>(a);
            accf[r] = a;
        }

        // this lane's gate pre-activations (gate q, both cells)
        float a01 = (q & 1) ? accf[1] : accf[0];
        float a23 = (q & 1) ? accf[3] : accf[2];
        float x0  = ((q & 2) ? a23 : a01) + p0;
        float b01 = (q & 1) ? accf[5] : accf[4];
        float b23 = (q & 1) ? accf[7] : accf[6];
        float x1  = ((q & 2) ? b23 : b01) + p1;
        float sv0 = frcp(1.f + fexp2(x0 * sc));
        float sv1 = frcp(1.f + fexp2(x1 * sc));

        // share gates within the quad
        float vi0 = dpp_f<DPP_BC0>(sv0), vf0 = dpp_f<DPP_BC1>(sv0);
        float vg0 = dpp_f<DPP_BC2>(sv0), vo0 = dpp_f<DPP_BC3>(sv0);
        float vi1 = dpp_f<DPP_BC0>(sv1), vf1 = dpp_f<DPP_BC1>(sv1);
        float vg1 = dpp_f<DPP_BC2>(sv1), vo1 = dpp_f<DPP_BC3>(sv1);

        // both cells updated redundantly in all 4 lanes
        float tg0 = fmaf(2.f, vg0, -1.f);
        c0v = fmaf(vf0, c0v, vi0*tg0);
        float th0 = fmaf(-2.f, frcp(1.f + fexp2(TWO_LOG2E*c0v)), 1.f);
        float h0v = vo0 * th0;

        float tg1 = fmaf(2.f, vg1, -1.f);
        c1v = fmaf(vf1, c1v, vi1*tg1);
        float th1 = fmaf(-2.f, frcp(1.f + fexp2(TWO_LOG2E*c1v)), 1.f);
        float h1v = vo1 * th1;

        if (sub < 2) hbuf[(s & 1) ^ 1][j0 + sub] = sub ? h1v : h0v;
        __syncthreads();

        hpv0 = h0v; hpv1 = h1v;
        p0 = pn0;  p1 = pn1;
    }

    // final step's hout store
    const int tl = t0 + dt*511;
    if (sub == 2) hout[tl*256 + houtbase + j0] = hpv0;
    if (sub == 3) hout[tl*256 + houtbase + j1] = hpv1;
}

// --------- score: S[n][m] = sum_h w2[h]*tanh(A+B+b1) + b2, diag=0 -----------
__global__ __launch_bounds__(256) void score_kernel(
    const float* __restrict__ Ap, const float* __restrict__ Bp,
    const float* __restrict__ W2, const float* __restrict__ b2p,
    float* __restrict__ S, float* __restrict__ csum)
{
    __shared__ __align__(16) float As[32*132];
    __shared__ __align__(16) float Bs[16*132];
    __shared__ __align__(16) float W2s[128];
    __shared__ float ps[16][17];
    int tid = threadIdx.x;
    int tx = tid & 15, ty = tid >> 4;
    int m0 = blockIdx.x*16, n0 = blockIdx.y*32;
    float acc0 = 0.f, acc1 = 0.f;

    for (int hc = 0; hc < 512; hc += 128) {
        #pragma unroll
        for (int i = 0; i < 4; ++i) {
            int idx = tid + 256*i;
            int row = idx >> 5, c4 = idx & 31;
            *(float4*)&As[row*132 + c4*4] = *(const float4*)(Ap + (n0+row)*512 + hc + c4*4);
        }
        #pragma unroll
        for (int i = 0; i < 2; ++i) {
            int idx = tid + 256*i;
            int row = idx >> 5, c4 = idx & 31;
            *(float4*)&Bs[row*132 + c4*4] = *(const float4*)(Bp + (m0+row)*512 + hc + c4*4);
        }
        if (tid < 128) W2s[tid] = W2[hc + tid];
        __syncthreads();

        #pragma unroll 4
        for (int h4 = 0; h4 < 32; ++h4) {
            float4 a0 = *(const float4*)&As[ty*132 + 4*h4];
            float4 a1 = *(const float4*)&As[(ty+16)*132 + 4*h4];
            float4 bv = *(const float4*)&Bs[tx*132 + 4*h4];
            float4 w4 = *(const float4*)&W2s[4*h4];
            float aa0[4] = {a0.x,a0.y,a0.z,a0.w};
            float aa1[4] = {a1.x,a1.y,a1.z,a1.w};
            float bb[4]  = {bv.x,bv.y,bv.z,bv.w};
            float ww[4]  = {w4.x,w4.y,w4.z,w4.w};
            #pragma unroll
            for (int qi = 0; qi < 4; ++qi) {
                float r0v = frcp(1.f + fexp2(aa0[qi] + bb[qi]));
                float r1v = frcp(1.f + fexp2(aa1[qi] + bb[qi]));
                acc0 = fmaf(ww[qi], fmaf(-2.f, r0v, 1.f), acc0);
                acc1 = fmaf(ww[qi], fmaf(-2.f, r1v, 1.f), acc1);
            }
        }
        __syncthreads();
    }

    float b2s = b2p[0];
    int gm  = m0 + tx;
    int gn0 = n0 + ty;
    int gn1 = n0 + 16 + ty;
    float v0 = acc0 + b2s; if (gn0 == gm) v0 = 0.f;
    float v1 = acc1 + b2s; if (gn1 == gm) v1 = 0.f;
    S[gn0*512 + gm] = v0;
    S[gn1*512 + gm] = v1;

    ps[ty][tx] = v0 + v1;
    __syncthreads();
    if (tid < 16) {
        float s = 0.f;
        #pragma unroll
        for (int k = 0; k < 16; ++k) s += ps[k][tid];
        atomicAdd(&csum[m0 + tid], s);
    }
}

// ---------------- row softmax of S[n][m]/csum[m] ----------------
__global__ __launch_bounds__(256) void softmax_kernel(const float* __restrict__ S,
                                                      const float* __restrict__ csum,
                                                      float* __restrict__ out)
{
    int n = blockIdx.x, tid = threadIdx.x;
    float v0 = S[n*512 + tid]       / csum[tid];
    float v1 = S[n*512 + tid + 256] / csum[tid + 256];

    __shared__ float rbuf[4], rbuf2[4];
    int wid = tid >> 6;

    float mx = fmaxf(v0, v1);
    #pragma unroll
    for (int off = 32; off; off >>= 1) mx = fmaxf(mx, __shfl_xor(mx, off, 64));
    if ((tid & 63) == 0) rbuf[wid] = mx;
    __syncthreads();
    mx = fmaxf(fmaxf(rbuf[0], rbuf[1]), fmaxf(rbuf[2], rbuf[3]));

    float e0 = fexp2((v0 - mx)*LOG2E);
    float e1 = fexp2((v1 - mx)*LOG2E);
    float sm = e0 + e1;
    #pragma unroll
    for (int off = 32; off; off >>= 1) sm += __shfl_xor(sm, off, 64);
    if ((tid & 63) == 0) rbuf2[wid] = sm;
    __syncthreads();
    sm = (rbuf2[0] + rbuf2[1]) + (rbuf2[2] + rbuf2[3]);

    float inv = 1.0f / sm;
    out[n*512 + tid]       = e0*inv;
    out[n*512 + tid + 256] = e1*inv;
}

extern "C" void kernel_launch(void* const* d_in, const int* in_sizes, int n_in,
                              void* d_out, int out_size, void* d_ws, size_t ws_size,
                              hipStream_t stream)
{
    const int*   wid  = (const int*)d_in[0];
    const int*   tgi  = (const int*)d_in[1];
    const float* wemb = (const float*)d_in[2];
    const float* temb = (const float*)d_in[3];
    const float* h0   = (const float*)d_in[4];
    const float* c0   = (const float*)d_in[5];
    const float* Wih0f=(const float*)d_in[6],  *Whh0f=(const float*)d_in[7],  *bih0f=(const float*)d_in[8],  *bhh0f=(const float*)d_in[9];
    const float* Wih0b=(const float*)d_in[10], *Whh0b=(const float*)d_in[11], *bih0b=(const float*)d_in[12], *bhh0b=(const float*)d_in[13];
    const float* Wih1f=(const float*)d_in[14], *Whh1f=(const float*)d_in[15], *bih1f=(const float*)d_in[16], *bhh1f=(const float*)d_in[17];
    const float* Wih1b=(const float*)d_in[18], *Whh1b=(const float*)d_in[19], *bih1b=(const float*)d_in[20], *bhh1b=(const float*)d_in[21];
    const float* W1   = (const float*)d_in[22];
    const float* b1   = (const float*)d_in[23];
    const float* W2   = (const float*)d_in[24];
    const float* b2   = (const float*)d_in[25];

    float* ws    = (float*)d_ws;
    float* h0cat = ws;              // [0, 131072)
    float* h1cat = ws + 131072;     // [131072, 262144)
    float* pA    = ws + 262144;     // [262144, 524288)
    float* pB    = ws + 524288;     // [524288, 786432)
    float* S     = ws;              // [0, 262144)  (h0cat/h1cat dead by score)
    float* csum  = ws + 786432;     // [786432, 786944)
    float* out   = (float*)d_out;

    gemm_l0<<<dim3(8,8,2), 256, 0, stream>>>(wid, tgi, wemb, temb,
                                             Wih0f, Wih0b, bih0f, bih0b, bhh0f, bhh0b,
                                             pA, pB, csum);
    lstm_kernel<<<2, 256, 0, stream>>>(pA, pB, Whh0f, Whh0b, h0, c0, h0cat, 0);

    gemm2<<<dim3(8,8,2), 256, 0, stream>>>(h0cat, 256, Wih1f, Wih1b, 256, 0,
                                           bih1f, bih1b, bhh1f, bhh1b,
                                           pA, pB, 256, 1.0f);
    lstm_kernel<<<2, 256, 0, stream>>>(pA, pB, Whh1f, Whh1b, h0, c0, h1cat, 1);

    gemm2<<<dim3(8,8,2), 256, 0, stream>>>(h1cat, 256, W1, W1, 512, 256,
                                           b1, nullptr, nullptr, nullptr,
                                           pA, pB, 256, TWO_LOG2E);

    score_kernel<<<dim3(32,16), 256, 0, stream>>>(pA, pB, W2, b2, S, csum);
    softmax_kernel<<<512, 256, 0, stream>>>(S, csum, out);
}

// Round 6
// 757.073 us; speedup vs baseline: 1.3360x; 1.3360x over previous
//
#include <hip/hip_runtime.h>

#define LOG2E 1.4426950408889634f
#define TWO_LOG2E 2.8853900817779268f

#if __has_builtin(__builtin_amdgcn_exp2f)
__device__ __forceinline__ float fexp2(float x){ return __builtin_amdgcn_exp2f(x); }
#else
__device__ __forceinline__ float fexp2(float x){ return exp2f(x); }
#endif
#if __has_builtin(__builtin_amdgcn_rcpf)
__device__ __forceinline__ float frcp(float x){ return __builtin_amdgcn_rcpf(x); }
#else
__device__ __forceinline__ float frcp(float x){ return 1.0f/(x); }
#endif

// DPP cross-lane move (full-rate VALU, no LDS pipe)
template<int CTRL>
__device__ __forceinline__ float dpp_f(float x) {
    return __int_as_float(__builtin_amdgcn_update_dpp(0, __float_as_int(x), CTRL, 0xF, 0xF, true));
}
#define DPP_XOR1  0xB1   // quad_perm(1,0,3,2)
#define DPP_XOR2  0x4E   // quad_perm(2,3,0,1)
#define DPP_BC0   0x00   // quad bcast lane0
#define DPP_BC1   0x55
#define DPP_BC2   0xAA
#define DPP_BC3   0xFF

// ---- layer-0 pre GEMM with fused embedding gather + csum zeroing ----------
__global__ __launch_bounds__(256) void gemm_l0(
    const int* __restrict__ wid, const int* __restrict__ tgi,
    const float* __restrict__ wemb, const float* __restrict__ temb,
    const float* __restrict__ Wa, const float* __restrict__ Wb,
    const float* __restrict__ b1a, const float* __restrict__ b1b,
    const float* __restrict__ b2a, const float* __restrict__ b2b,
    float* __restrict__ Ca, float* __restrict__ Cb,
    float* __restrict__ csum)
{
    int tid = threadIdx.x;
    if (blockIdx.x == 0 && blockIdx.y == 0 && blockIdx.z == 0) {
        csum[tid] = 0.f; csum[tid + 256] = 0.f;   // zero for score's atomics
    }
    int z = blockIdx.z;
    const float* W   = z ? Wb  : Wa;
    const float* bb1 = z ? b1b : b1a;
    const float* bb2 = z ? b2b : b2a;
    float* C = z ? Cb : Ca;

    __shared__ float Xs[64*33];
    __shared__ float Ws[64*33];
    int tx = tid & 15, ty = tid >> 4;
    int n0 = blockIdx.y*64, r0 = blockIdx.x*64;
    float acc[4][4] = {};

    for (int k0 = 0; k0 < 128; k0 += 32) {
        #pragma unroll
        for (int i = 0; i < 2; ++i) {
            int idx = tid + 256*i;
            int row = idx >> 3, c4 = idx & 7;
            int k = k0 + c4*4;
            int rg = n0 + row;
            float4 vx = (k < 100) ? *(const float4*)(wemb + wid[rg]*100 + k)
                                  : *(const float4*)(temb + tgi[rg]*28 + (k-100));
            float4 vw = *(const float4*)(W + (r0+row)*128 + k0 + c4*4);
            Xs[row*33 + c4*4+0]=vx.x; Xs[row*33 + c4*4+1]=vx.y; Xs[row*33 + c4*4+2]=vx.z; Xs[row*33 + c4*4+3]=vx.w;
            Ws[row*33 + c4*4+0]=vw.x; Ws[row*33 + c4*4+1]=vw.y; Ws[row*33 + c4*4+2]=vw.z; Ws[row*33 + c4*4+3]=vw.w;
        }
        __syncthreads();
        #pragma unroll 8
        for (int kk = 0; kk < 32; ++kk) {
            float a[4], b[4];
            #pragma unroll
            for (int i = 0; i < 4; ++i) a[i] = Xs[(4*ty+i)*33 + kk];
            #pragma unroll
            for (int j = 0; j < 4; ++j) b[j] = Ws[(4*tx+j)*33 + kk];
            #pragma unroll
            for (int i = 0; i < 4; ++i)
                #pragma unroll
                for (int j = 0; j < 4; ++j)
                    acc[i][j] = fmaf(a[i], b[j], acc[i][j]);
        }
        __syncthreads();
    }
    #pragma unroll
    for (int i = 0; i < 4; ++i)
        #pragma unroll
        for (int j = 0; j < 4; ++j) {
            int r = r0 + 4*tx + j;
            C[(n0 + 4*ty + i)*512 + r] = acc[i][j] + bb1[r] + bb2[r];
        }
}

// ------------- generic fused-pair GEMM: C[n][r] = scale*(X·W^T + b1 + b2) ----
__global__ __launch_bounds__(256) void gemm2(
    const float* __restrict__ X, int ldx,
    const float* __restrict__ Wa, const float* __restrict__ Wb, int ldw, int woffb,
    const float* __restrict__ b1a, const float* __restrict__ b1b,
    const float* __restrict__ b2a, const float* __restrict__ b2b,
    float* __restrict__ Ca, float* __restrict__ Cb,
    int K, float scale)
{
    int z = blockIdx.z;
    const float* W  = z ? Wb  : Wa;
    const float* bb1 = z ? b1b : b1a;
    const float* bb2 = z ? b2b : b2a;
    float* C = z ? Cb : Ca;
    int woff = z ? woffb : 0;

    __shared__ float Xs[64*33];
    __shared__ float Ws[64*33];
    int tid = threadIdx.x;
    int tx = tid & 15, ty = tid >> 4;
    int n0 = blockIdx.y*64, r0 = blockIdx.x*64;
    float acc[4][4] = {};

    for (int k0 = 0; k0 < K; k0 += 32) {
        #pragma unroll
        for (int i = 0; i < 2; ++i) {
            int idx = tid + 256*i;
            int row = idx >> 3, c4 = idx & 7;
            float4 vx = *(const float4*)(X + (n0+row)*ldx + k0 + c4*4);
            float4 vw = *(const float4*)(W + (r0+row)*ldw + woff + k0 + c4*4);
            Xs[row*33 + c4*4+0]=vx.x; Xs[row*33 + c4*4+1]=vx.y; Xs[row*33 + c4*4+2]=vx.z; Xs[row*33 + c4*4+3]=vx.w;
            Ws[row*33 + c4*4+0]=vw.x; Ws[row*33 + c4*4+1]=vw.y; Ws[row*33 + c4*4+2]=vw.z; Ws[row*33 + c4*4+3]=vw.w;
        }
        __syncthreads();
        #pragma unroll 8
        for (int kk = 0; kk < 32; ++kk) {
            float a[4], b[4];
            #pragma unroll
            for (int i = 0; i < 4; ++i) a[i] = Xs[(4*ty+i)*33 + kk];
            #pragma unroll
            for (int j = 0; j < 4; ++j) b[j] = Ws[(4*tx+j)*33 + kk];
            #pragma unroll
            for (int i = 0; i < 4; ++i)
                #pragma unroll
                for (int j = 0; j < 4; ++j)
                    acc[i][j] = fmaf(a[i], b[j], acc[i][j]);
        }
        __syncthreads();
    }
    #pragma unroll
    for (int i = 0; i < 4; ++i)
        #pragma unroll
        for (int j = 0; j < 4; ++j) {
            int r = r0 + 4*tx + j;
            float v = acc[i][j];
            if (bb1) v += bb1[r];
            if (bb2) v += bb2[r];
            C[(n0 + 4*ty + i)*512 + r] = v*scale;
        }
}

// ---------------- LSTM: 512 threads, 128 weights/thread (C=32, R=4) ---------
// lane: sub = tid&3 (col slice of 32 cols), cell j = tid>>2, owns all 4
// gate-rows of cell j over its 32 cols. 128 scalar fmaf/lane with weights in
// AGPRs (scalar v_fmac can source AGPR; VOP3P pk_fma cannot — R4/R5 lesson).
// 2-step quad DPP butterfly reduce; gate sub's sigmoid per lane; quad DPP
// broadcast; h ping-pong in LDS, one barrier/step.
__global__ __launch_bounds__(512, 2) void lstm_kernel(
    const float* __restrict__ preF, const float* __restrict__ preB,
    const float* __restrict__ WhhF, const float* __restrict__ WhhB,
    const float* __restrict__ h0, const float* __restrict__ c0,
    float* __restrict__ hout, int layer)
{
    const int dir = blockIdx.x;
    const int tid = threadIdx.x;
    const int sub = tid & 3;        // col slice 0..3
    const int j   = tid >> 2;       // cell 0..127
    const int q   = sub;            // gate handled by this lane's transcendental
    const float* Whh  = dir ? WhhB : WhhF;
    const float* preD = dir ? preB : preF;

    // chunk schedule: instr k -> absolute float4 chunk cidx[k] in [8sub, 8sub+8).
    // At each k the 4 subs hit bank-groups (k)&7,(k+2)&7,(k+4)&7,(k+6)&7 —
    // 4 disjoint 4-bank groups; 16 cells broadcast the same address (free).
    int cidx[8];
    #pragma unroll
    for (int k = 0; k < 8; ++k) cidx[k] = (sub << 3) + ((k + 2*sub) & 7);

    // weights w[r][4k+m] = Whh[(r<<7)+j][4*cidx[k]+m]  (AGPR-resident)
    float w[4][32];
    #pragma unroll
    for (int r = 0; r < 4; ++r) {
        const float* wr = Whh + ((r << 7) + j)*128;
        #pragma unroll
        for (int k = 0; k < 8; ++k) {
            float4 v = *(const float4*)(wr + 4*cidx[k]);
            w[r][4*k+0]=v.x; w[r][4*k+1]=v.y; w[r][4*k+2]=v.z; w[r][4*k+3]=v.w;
        }
    }

    __shared__ __align__(16) float hbuf[2][128];

    const float* h0d = h0 + (2*layer + dir)*128;
    const float* c0d = c0 + (2*layer + dir)*128;
    float c = c0d[j];
    if (tid < 128) hbuf[0][tid] = h0d[tid];

    const float sc = (q == 2) ? -TWO_LOG2E : -LOG2E;   // gate 2: sigm(2*gg)
    const int prow = (q << 7) + j;
    const int t0 = dir ? 511 : 0;
    const int dt = dir ? -1 : 1;

    float pcur = preD[t0*512 + prow];
    __syncthreads();

    #pragma unroll 2
    for (int s = 0; s < 512; ++s) {
        const int t  = t0 + dt*s;
        const int tn = (s < 511) ? (t + dt) : t;
        float pnext = preD[tn*512 + prow];

        const int p = s & 1;
        const float4* h4 = (const float4*)hbuf[p];
        float4 hv[8];
        #pragma unroll
        for (int k = 0; k < 8; ++k) hv[k] = h4[cidx[k]];

        float acc[4] = {0.f, 0.f, 0.f, 0.f};
        #pragma unroll
        for (int k = 0; k < 8; ++k) {
            #pragma unroll
            for (int r = 0; r < 4; ++r) {
                acc[r] = fmaf(hv[k].x, w[r][4*k+0], acc[r]);
                acc[r] = fmaf(hv[k].y, w[r][4*k+1], acc[r]);
                acc[r] = fmaf(hv[k].z, w[r][4*k+2], acc[r]);
                acc[r] = fmaf(hv[k].w, w[r][4*k+3], acc[r]);
            }
        }

        // butterfly reduce over the 4 col-slices (quad DPP)
        #pragma unroll
        for (int r = 0; r < 4; ++r) {
            acc[r] += dpp_f<DPP_XOR1>(acc[r]);
            acc[r] += dpp_f<DPP_XOR2>(acc[r]);
        }

        // this lane's gate pre-activation (gate q)
        float a01 = (q & 1) ? acc[1] : acc[0];
        float a23 = (q & 1) ? acc[3] : acc[2];
        float xg  = (((q & 2) ? a23 : a01) + pcur) * sc;
        float sv  = frcp(1.f + fexp2(xg));

        // share the four gates within the quad
        float vi = dpp_f<DPP_BC0>(sv);
        float vf = dpp_f<DPP_BC1>(sv);
        float vg = dpp_f<DPP_BC2>(sv);
        float vo = dpp_f<DPP_BC3>(sv);

        float tg = fmaf(2.f, vg, -1.f);           // tanh(gg)
        c = fmaf(vf, c, vi*tg);
        float th = fmaf(-2.f, frcp(1.f + fexp2(TWO_LOG2E*c)), 1.f);  // tanh(c)
        float h  = vo * th;

        if (sub == 1) hbuf[p ^ 1][j] = h;
        if (sub == 2) hout[t*256 + dir*128 + j] = h;   // overlapped w/ barrier
        __syncthreads();
        pcur = pnext;
    }
}

// --------- score: S[n][m] = sum_h w2[h]*tanh(A+B+b1) + b2, diag=0 -----------
__global__ __launch_bounds__(256) void score_kernel(
    const float* __restrict__ Ap, const float* __restrict__ Bp,
    const float* __restrict__ W2, const float* __restrict__ b2p,
    float* __restrict__ S, float* __restrict__ csum)
{
    __shared__ __align__(16) float As[32*132];
    __shared__ __align__(16) float Bs[16*132];
    __shared__ __align__(16) float W2s[128];
    __shared__ float ps[16][17];
    int tid = threadIdx.x;
    int tx = tid & 15, ty = tid >> 4;
    int m0 = blockIdx.x*16, n0 = blockIdx.y*32;
    float acc0 = 0.f, acc1 = 0.f;

    for (int hc = 0; hc < 512; hc += 128) {
        #pragma unroll
        for (int i = 0; i < 4; ++i) {
            int idx = tid + 256*i;
            int row = idx >> 5, c4 = idx & 31;
            *(float4*)&As[row*132 + c4*4] = *(const float4*)(Ap + (n0+row)*512 + hc + c4*4);
        }
        #pragma unroll
        for (int i = 0; i < 2; ++i) {
            int idx = tid + 256*i;
            int row = idx >> 5, c4 = idx & 31;
            *(float4*)&Bs[row*132 + c4*4] = *(const float4*)(Bp + (m0+row)*512 + hc + c4*4);
        }
        if (tid < 128) W2s[tid] = W2[hc + tid];
        __syncthreads();

        #pragma unroll 4
        for (int h4 = 0; h4 < 32; ++h4) {
            float4 a0 = *(const float4*)&As[ty*132 + 4*h4];
            float4 a1 = *(const float4*)&As[(ty+16)*132 + 4*h4];
            float4 bv = *(const float4*)&Bs[tx*132 + 4*h4];
            float4 w4 = *(const float4*)&W2s[4*h4];
            float aa0[4] = {a0.x,a0.y,a0.z,a0.w};
            float aa1[4] = {a1.x,a1.y,a1.z,a1.w};
            float bb[4]  = {bv.x,bv.y,bv.z,bv.w};
            float ww[4]  = {w4.x,w4.y,w4.z,w4.w};
            #pragma unroll
            for (int qi = 0; qi < 4; ++qi) {
                float r0v = frcp(1.f + fexp2(aa0[qi] + bb[qi]));
                float r1v = frcp(1.f + fexp2(aa1[qi] + bb[qi]));
                acc0 = fmaf(ww[qi], fmaf(-2.f, r0v, 1.f), acc0);
                acc1 = fmaf(ww[qi], fmaf(-2.f, r1v, 1.f), acc1);
            }
        }
        __syncthreads();
    }

    float b2s = b2p[0];
    int gm  = m0 + tx;
    int gn0 = n0 + ty;
    int gn1 = n0 + 16 + ty;
    float v0 = acc0 + b2s; if (gn0 == gm) v0 = 0.f;
    float v1 = acc1 + b2s; if (gn1 == gm) v1 = 0.f;
    S[gn0*512 + gm] = v0;
    S[gn1*512 + gm] = v1;

    ps[ty][tx] = v0 + v1;
    __syncthreads();
    if (tid < 16) {
        float s = 0.f;
        #pragma unroll
        for (int k = 0; k < 16; ++k) s += ps[k][tid];
        atomicAdd(&csum[m0 + tid], s);
    }
}

// ---------------- row softmax of S[n][m]/csum[m] ----------------
__global__ __launch_bounds__(256) void softmax_kernel(const float* __restrict__ S,
                                                      const float* __restrict__ csum,
                                                      float* __restrict__ out)
{
    int n = blockIdx.x, tid = threadIdx.x;
    float v0 = S[n*512 + tid]       / csum[tid];
    float v1 = S[n*512 + tid + 256] / csum[tid + 256];

    __shared__ float rbuf[4], rbuf2[4];
    int wid = tid >> 6;

    float mx = fmaxf(v0, v1);
    #pragma unroll
    for (int off = 32; off; off >>= 1) mx = fmaxf(mx, __shfl_xor(mx, off, 64));
    if ((tid & 63) == 0) rbuf[wid] = mx;
    __syncthreads();
    mx = fmaxf(fmaxf(rbuf[0], rbuf[1]), fmaxf(rbuf[2], rbuf[3]));

    float e0 = fexp2((v0 - mx)*LOG2E);
    float e1 = fexp2((v1 - mx)*LOG2E);
    float sm = e0 + e1;
    #pragma unroll
    for (int off = 32; off; off >>= 1) sm += __shfl_xor(sm, off, 64);
    if ((tid & 63) == 0) rbuf2[wid] = sm;
    __syncthreads();
    sm = (rbuf2[0] + rbuf2[1]) + (rbuf2[2] + rbuf2[3]);

    float inv = 1.0f / sm;
    out[n*512 + tid]       = e0*inv;
    out[n*512 + tid + 256] = e1*inv;
}

extern "C" void kernel_launch(void* const* d_in, const int* in_sizes, int n_in,
                              void* d_out, int out_size, void* d_ws, size_t ws_size,
                              hipStream_t stream)
{
    const int*   wid  = (const int*)d_in[0];
    const int*   tgi  = (const int*)d_in[1];
    const float* wemb = (const float*)d_in[2];
    const float* temb = (const float*)d_in[3];
    const float* h0   = (const float*)d_in[4];
    const float* c0   = (const float*)d_in[5];
    const float* Wih0f=(const float*)d_in[6],  *Whh0f=(const float*)d_in[7],  *bih0f=(const float*)d_in[8],  *bhh0f=(const float*)d_in[9];
    const float* Wih0b=(const float*)d_in[10], *Whh0b=(const float*)d_in[11], *bih0b=(const float*)d_in[12], *bhh0b=(const float*)d_in[13];
    const float* Wih1f=(const float*)d_in[14], *Whh1f=(const float*)d_in[15], *bih1f=(const float*)d_in[16], *bhh1f=(const float*)d_in[17];
    const float* Wih1b=(const float*)d_in[18], *Whh1b=(const float*)d_in[19], *bih1b=(const float*)d_in[20], *bhh1b=(const float*)d_in[21];
    const float* W1   = (const float*)d_in[22];
    const float* b1   = (const float*)d_in[23];
    const float* W2   = (const float*)d_in[24];
    const float* b2   = (const float*)d_in[25];

    float* ws    = (float*)d_ws;
    float* h0cat = ws;              // [0, 131072)
    float* h1cat = ws + 131072;     // [131072, 262144)
    float* pA    = ws + 262144;     // [262144, 524288)
    float* pB    = ws + 524288;     // [524288, 786432)
    float* S     = ws;              // [0, 262144)  (h0cat/h1cat dead by score)
    float* csum  = ws + 786432;     // [786432, 786944)
    float* out   = (float*)d_out;

    gemm_l0<<<dim3(8,8,2), 256, 0, stream>>>(wid, tgi, wemb, temb,
                                             Wih0f, Wih0b, bih0f, bih0b, bhh0f, bhh0b,
                                             pA, pB, csum);
    lstm_kernel<<<2, 512, 0, stream>>>(pA, pB, Whh0f, Whh0b, h0, c0, h0cat, 0);

    gemm2<<<dim3(8,8,2), 256, 0, stream>>>(h0cat, 256, Wih1f, Wih1b, 256, 0,
                                           bih1f, bih1b, bhh1f, bhh1b,
                                           pA, pB, 256, 1.0f);
    lstm_kernel<<<2, 512, 0, stream>>>(pA, pB, Whh1f, Whh1b, h0, c0, h1cat, 1);

    gemm2<<<dim3(8,8,2), 256, 0, stream>>>(h1cat, 256, W1, W1, 512, 256,
                                           b1, nullptr, nullptr, nullptr,
                                           pA, pB, 256, TWO_LOG2E);

    score_kernel<<<dim3(32,16), 256, 0, stream>>>(pA, pB, W2, b2, S, csum);
    softmax_kernel<<<512, 256, 0, stream>>>(S, csum, out);
}